// Round 5
// baseline (118.229 us; speedup 1.0000x reference)
//
#include <hip/hip_runtime.h>
#include <cstdint>
#include <cstddef>

#define LDIM 6
#define BDIM 4
#define QDIM 900
#define CDIM 256
#define NDIM (LDIM*QDIM)   /* 5400 */
#define NN   5408          /* padded per-image stride */
#define T128 43            /* ceil(5400/128) */
#define NT128 (T128*(T128+1)/2) /* 946 lower-tri 128x128 tiles */

/* per-image header slots padded to one 64B cache line each to avoid
   same-line atomic serialization across blocks/images */
#define HS4 16   /* stride in ints   (64 B) */
#define HS8 8    /* stride in u64    (64 B) */

typedef float floatx4 __attribute__((ext_vector_type(4)));

__device__ __forceinline__ int sig_off(int b, int n) {
    int l = n / QDIM, q = n - l * QDIM;
    return ((l * BDIM + b) * QDIM + q) * CDIM;
}
__device__ __forceinline__ int logit_off(int b, int n) {
    int l = n / QDIM, q = n - l * QDIM;
    return (l * BDIM + b) * QDIM + q;
}

__device__ __forceinline__ int uf_load(const int* p, int i) {
    return __hip_atomic_load(&p[i], __ATOMIC_RELAXED, __HIP_MEMORY_SCOPE_AGENT);
}
__device__ int uf_find(int* p, int x) {
    int r = x;
    int pr = uf_load(p, r);
    while (pr != r) { r = pr; pr = uf_load(p, r); }
    return r;
}
__device__ void uf_union(int* p, int a, int b) {
    int ra = uf_find(p, a), rb = uf_find(p, b);
    while (ra != rb) {
        int hi = ra > rb ? ra : rb;
        int lo = ra ^ rb ^ hi;
        int old = atomicCAS(&p[hi], hi, lo);
        if (old == hi) return;
        ra = uf_find(p, old);
        rb = uf_find(p, lo);
    }
}

__device__ __forceinline__ int pk_fp8x4(float a, float b, float c, float d) {
    int p = __builtin_amdgcn_cvt_pk_fp8_f32(a, b, 0, false);   // bytes 0,1
    p = __builtin_amdgcn_cvt_pk_fp8_f32(c, d, p, true);        // bytes 2,3
    return p;
}

// Convert one sig row to normalized fp8 at compacted slot g (full wave).
__device__ __forceinline__ void cvt_row(const float4 v, int g, int lane,
                                        char* __restrict__ Xf8, int b) {
    float s = v.x * v.x + v.y * v.y + v.z * v.z + v.w * v.w;
    for (int off = 32; off; off >>= 1) s += __shfl_down(s, off);
    s = __shfl(s, 0);
    float ninv = rsqrtf(s + 1e-12f);
    int p = pk_fp8x4(v.x * ninv, v.y * ninv, v.z * ninv, v.w * ninv);
    int slot = (lane >> 2) ^ (g & 15);
    *(int*)(Xf8 + ((size_t)(b * NN + g)) * 256 + slot * 16 + (lane & 3) * 4) = p;
}

// K1: fused init + fp8 conversion. 256 thr / 256 nodes per block.
// Per wave: scores/parent/compKey init + ballot slot-claim; then the SAME wave
// converts its own claimed rows (no cross-block dependency), 4-deep load-batched
// so row loads pipeline. argKey atomics only from waves with cnt==0 (valid:
// any cnt>0 => Mcnt>0 => fallback never reads argKey). Last-done block: fallback.
__global__ __launch_bounds__(256) void k_initf(const float* __restrict__ logits,
                                               const float* __restrict__ sig,
                                               float* __restrict__ scores,
                                               int* __restrict__ parent,
                                               unsigned long long* __restrict__ compKey,
                                               int* __restrict__ selIdx,
                                               int* __restrict__ Mcnt,
                                               unsigned long long* __restrict__ argKey,
                                               int* __restrict__ done,
                                               char* __restrict__ Xf8) {
    int b = blockIdx.y;
    int tid = threadIdx.x;
    int lane = tid & 63, wave = tid >> 6;
    int n = blockIdx.x * 256 + tid;
    __shared__ int selNodeSh[4][64];

    if (n < NN) compKey[b * NN + n] = 0ULL;
    int f = 0;
    float sc = 0.0f;
    if (n < NDIM) {
        float x = logits[logit_off(b, n)];
        sc = 1.0f / (1.0f + expf(-x));
        scores[b * NN + n] = sc;
        parent[b * NN + n] = n;
        f = (sc >= 0.5f) ? 1 : 0;
    }
    unsigned long long bal = __ballot(f != 0);
    int cnt = __popcll(bal);
    int rank = __popcll(bal & ((1ull << lane) - 1ull));
    int base = 0;
    if (lane == 0 && cnt) base = atomicAdd(&Mcnt[b * HS4], cnt);
    base = __shfl(base, 0);
    if (f) {
        selIdx[b * NN + base + rank] = n;
        selNodeSh[wave][rank] = n;
    }

    // argmax contribution only needed if this wave selected nothing
    int waveBase = blockIdx.x * 256 + wave * 64;
    if (cnt == 0 && waveBase < NDIM) {
        unsigned long long key = 0ULL;
        if (n < NDIM)
            key = ((unsigned long long)__float_as_uint(sc) << 32) | (unsigned int)(~n);
        for (int off = 32; off; off >>= 1) {
            unsigned long long o = __shfl_down(key, off);
            if (o > key) key = o;
        }
        if (lane == 0) atomicMax(&argKey[b * HS8], key);
    }

    // convert this wave's claimed rows, 4-deep batches (loads in flight together)
    for (int i0 = 0; i0 < cnt; i0 += 4) {
        int m = cnt - i0;
        float4 v0, v1, v2, v3;
        int n0 = selNodeSh[wave][i0];
        v0 = *(const float4*)(sig + sig_off(b, n0) + lane * 4);
        if (m > 1) { int n1 = selNodeSh[wave][i0 + 1];
                     v1 = *(const float4*)(sig + sig_off(b, n1) + lane * 4); }
        if (m > 2) { int n2 = selNodeSh[wave][i0 + 2];
                     v2 = *(const float4*)(sig + sig_off(b, n2) + lane * 4); }
        if (m > 3) { int n3 = selNodeSh[wave][i0 + 3];
                     v3 = *(const float4*)(sig + sig_off(b, n3) + lane * 4); }
        cvt_row(v0, base + i0, lane, Xf8, b);
        if (m > 1) cvt_row(v1, base + i0 + 1, lane, Xf8, b);
        if (m > 2) cvt_row(v2, base + i0 + 2, lane, Xf8, b);
        if (m > 3) cvt_row(v3, base + i0 + 3, lane, Xf8, b);
    }

    // ---- done counter: last block runs the (rare) argmax fallback ----
    __shared__ int lastSh;
    __shared__ int bestSh;
    __syncthreads();
    if (tid == 0) {
        int prev = __hip_atomic_fetch_add(&done[b * HS4], 1, __ATOMIC_ACQ_REL,
                                          __HIP_MEMORY_SCOPE_AGENT);
        lastSh = (prev == (int)gridDim.x - 1) ? 1 : 0;
    }
    __syncthreads();
    if (!lastSh) return;
    if (__hip_atomic_load(&Mcnt[b * HS4], __ATOMIC_RELAXED,
                          __HIP_MEMORY_SCOPE_AGENT) != 0) return;

    if (tid == 0) {
        unsigned long long k = __hip_atomic_load(&argKey[b * HS8], __ATOMIC_RELAXED,
                                                 __HIP_MEMORY_SCOPE_AGENT);
        int best = (int)(~(unsigned int)(k & 0xffffffffULL));
        selIdx[b * NN + 0] = best;
        __hip_atomic_store(&Mcnt[b * HS4], 1, __ATOMIC_RELAXED,
                           __HIP_MEMORY_SCOPE_AGENT);
        bestSh = best;
    }
    __syncthreads();
    if (wave == 0) {
        const float4 v = *(const float4*)(sig + sig_off(b, bestSh) + lane * 4);
        cvt_row(v, 0, lane, Xf8, b);
    }
}

// K2: fp8 MFMA pairwise sims, 128x128 tiles. B tile (128 rows, 32 KB) staged to LDS;
// A rows direct from global. 16 MFMA per K-step per wave.
__global__ __launch_bounds__(256) void k_sim_mfma(const char* __restrict__ Xf8,
                                                  const int* __restrict__ selIdx,
                                                  const int* __restrict__ Mcnt,
                                                  int* __restrict__ parent) {
    int bx = blockIdx.x;
    int b = bx & 3;            // image -> XCD locality
    int t = bx >> 2;
    int M = min(Mcnt[b * HS4], NDIM);   // clamp: bounded under rocprof replay
    int ti = (int)((sqrtf(8.0f * (float)t + 1.0f) - 1.0f) * 0.5f);
    while ((ti + 1) * (ti + 2) / 2 <= t) ti++;
    while (ti * (ti + 1) / 2 > t) ti--;
    int tj = t - ti * (ti + 1) / 2;
    if (M <= 0 || ti * 128 >= M) return;

    extern __shared__ char Bs[];   // 128 rows x 256 B (swizzled layout preserved)

    int tid = threadIdx.x;
    int lane = tid & 63, wave = tid >> 6;
    int rsel = lane & 15, quad = lane >> 4;

    // stage B rows [tj*128, +128): 32 x 1KB contiguous copies (4 rows each), 8 per wave
    const char* xb = Xf8 + ((size_t)b * NN) * 256;
#pragma unroll
    for (int k = 0; k < 8; k++) {
        int i = wave * 8 + k;
        int row = min(tj * 128 + 4 * i, NN - 4);
        const char* src = xb + (size_t)row * 256 + lane * 16;
        __builtin_amdgcn_global_load_lds(
            (const __attribute__((address_space(1))) unsigned int*)src,
            (__attribute__((address_space(3))) unsigned int*)(Bs + i * 1024),
            16, 0, 0);
    }

    // A rows: wave's 32-row slab (2 x 16)
    int rA = ti * 128 + wave * 32;
    int gA0 = min(rA + rsel, M - 1);
    int gA1 = min(rA + 16 + rsel, M - 1);
    const char* pA0 = Xf8 + ((size_t)(b * NN + gA0)) * 256;
    const char* pA1 = Xf8 + ((size_t)(b * NN + gA1)) * 256;
    int swA0 = gA0 & 15, swA1 = gA1 & 15;

    __syncthreads();   // drains global_load_lds

    floatx4 acc[2][8];
#pragma unroll
    for (int s = 0; s < 2; s++)
#pragma unroll
        for (int nj = 0; nj < 8; nj++) acc[s][nj] = (floatx4){0.f, 0.f, 0.f, 0.f};

#pragma unroll
    for (int ks = 0; ks < 8; ks++) {
        int ch = ks * 2 + (quad >> 1);       // logical 16B chunk of the 32B K-slab half
        int ih = (quad & 1) * 8;             // 8B half within chunk
        long a0 = *(const long*)(pA0 + ((ch ^ swA0) << 4) + ih);
        long a1 = *(const long*)(pA1 + ((ch ^ swA1) << 4) + ih);
#pragma unroll
        for (int nj = 0; nj < 8; nj++) {
            int lr = nj * 16 + rsel;
            long bb = *(const long*)(Bs + lr * 256 + (((ch ^ (lr & 15)) << 4) + ih));
            acc[0][nj] = __builtin_amdgcn_mfma_f32_16x16x32_fp8_fp8(a0, bb, acc[0][nj], 0, 0, 0);
            acc[1][nj] = __builtin_amdgcn_mfma_f32_16x16x32_fp8_fp8(a1, bb, acc[1][nj], 0, 0, 0);
        }
    }

#pragma unroll
    for (int s = 0; s < 2; s++) {
        int rowA = rA + s * 16 + quad * 4;
#pragma unroll
        for (int nj = 0; nj < 8; nj++) {
            int gj = tj * 128 + nj * 16 + rsel;
#pragma unroll
            for (int r = 0; r < 4; r++) {
                int gi = rowA + r;
                if (gi < M && gj < M && gi > gj && acc[s][nj][r] >= 0.8f) {
                    uf_union(parent + b * NN, selIdx[b * NN + gi], selIdx[b * NN + gj]);
                }
            }
        }
    }
}

// K3: component stats + ranking. One 1024-thr block per image.
// 16 parallel wave ranges, register-cached keys, 2 syncthreads total.
__global__ __launch_bounds__(1024) void k_comp(int* __restrict__ parent,
                                               const int* __restrict__ selIdx,
                                               const int* __restrict__ Mcnt,
                                               const float* __restrict__ scores,
                                               unsigned long long* __restrict__ compKey,
                                               int* __restrict__ seedNode,
                                               int* __restrict__ Scnt) {
    int b = blockIdx.x, t = threadIdx.x;
    int lane = t & 63, w = t >> 6;      // 16 waves
    __shared__ int wcnt[16];
    __shared__ int woff[16];

    // phase 1: per selected node, find root, max packed (score, ~idx) key
    int M = min(Mcnt[b * HS4], NDIM);   // clamp: bounded under rocprof replay
    for (int base = 0; base < M; base += 1024) {
        int g = base + t;
        if (g < M) {
            int node = selIdx[b * NN + g];
            int root = uf_find(parent + b * NN, node);
            unsigned long long key =
                ((unsigned long long)__float_as_uint(scores[b * NN + node]) << 32) |
                (unsigned int)(~node);
            atomicMax(&compKey[b * NN + root], key);
        }
    }
    __syncthreads();

    // phase 2 pass A: each wave counts seeded roots in its 384-entry range,
    // caching keys in registers (agent-scope loads to bypass stale L1).
#define CROUNDS 6   /* 16 waves * 6 rounds * 64 lanes = 6144 >= NDIM */
    unsigned long long kc[CROUNDS];
    int cnt = 0;
#pragma unroll
    for (int r = 0; r < CROUNDS; r++) {
        int n = (w * CROUNDS + r) * 64 + lane;
        unsigned long long key = 0ULL;
        if (n < NDIM)
            key = __hip_atomic_load(&compKey[b * NN + n], __ATOMIC_RELAXED,
                                    __HIP_MEMORY_SCOPE_AGENT);
        kc[r] = key;
        cnt += __popcll(__ballot(key != 0ULL));
    }
    if (lane == 0) wcnt[w] = cnt;
    __syncthreads();
    if (t == 0) {
        int s = 0;
        for (int i = 0; i < 16; i++) { int v = wcnt[i]; woff[i] = s; s += v; }
        Scnt[b * HS4] = s;
    }
    __syncthreads();

    // phase 2 pass B: scatter seeds at exclusive-scanned offsets, order preserved.
    int off = woff[w];
#pragma unroll
    for (int r = 0; r < CROUNDS; r++) {
        unsigned long long bal = __ballot(kc[r] != 0ULL);
        int rank = __popcll(bal & ((1ull << lane) - 1ull));
        if (kc[r] != 0ULL)
            seedNode[b * NN + off + rank] =
                (int)(~(unsigned int)(kc[r] & 0xffffffffULL));
        off += __popcll(bal);
    }
#undef CROUNDS
}

// K4: write seed signatures / mask / scores; zero-fill empty slots. 4 rows per block.
__global__ void k_write(const float* __restrict__ sig, const float* __restrict__ scores,
                        const int* __restrict__ seedNode, const int* __restrict__ Scnt,
                        float* __restrict__ out) {
    int b = blockIdx.y;
    int slot = blockIdx.x * 4 + (threadIdx.x >> 6);
    int lane = threadIdx.x & 63;
    int S = min(Scnt[b * HS4], NDIM);   // clamp: bounded under rocprof replay
    float* orow = out + ((size_t)(b * NDIM + slot)) * CDIM + lane * 4;
    if (slot < S) {
        int s = seedNode[b * NN + slot];
        float4 v = *(const float4*)(sig + sig_off(b, s) + lane * 4);
        *(float4*)orow = v;
        if (lane == 0) {
            out[(size_t)BDIM * NDIM * CDIM + (size_t)b * NDIM + slot] = 1.0f;
            out[(size_t)BDIM * NDIM * CDIM + (size_t)BDIM * NDIM + (size_t)b * NDIM + slot] =
                scores[b * NN + s];
        }
    } else {
        float4 z = {0.f, 0.f, 0.f, 0.f};
        *(float4*)orow = z;
        if (lane == 0) {
            out[(size_t)BDIM * NDIM * CDIM + (size_t)b * NDIM + slot] = 0.0f;
            out[(size_t)BDIM * NDIM * CDIM + (size_t)BDIM * NDIM + (size_t)b * NDIM + slot] = 0.0f;
        }
    }
}

extern "C" void kernel_launch(void* const* d_in, const int* in_sizes, int n_in,
                              void* d_out, int out_size, void* d_ws, size_t ws_size,
                              hipStream_t stream) {
    (void)in_sizes; (void)n_in; (void)out_size; (void)ws_size;
    const float* sig = (const float*)d_in[0];
    const float* logits = (const float*)d_in[1];
    float* out = (float*)d_out;
    char* ws = (char*)d_ws;

    // header: 4 arrays x 4 images x 64B/line = 1024 B
    int* Mcnt = (int*)(ws + 0);                        // [b*HS4], 256 B
    int* done = (int*)(ws + 256);                      // [b*HS4], 256 B
    unsigned long long* argKey = (unsigned long long*)(ws + 512);  // [b*HS8], 256 B
    int* Scnt = (int*)(ws + 768);                      // [b*HS4], 256 B

    const size_t arr = (size_t)BDIM * NN * 4;  // 86528 B per int/float array
    unsigned long long* compKey = (unsigned long long*)(ws + 1024); // 2*arr
    float* scores = (float*)(ws + 1024 + 2 * arr);
    int* parent   = (int*)(ws + 1024 + 3 * arr);
    int* selIdx   = (int*)(ws + 1024 + 4 * arr);
    int* seedNode = (int*)(ws + 1024 + 5 * arr);
    char* Xf8     = (char*)(ws + 1024 + 6 * arr);      // BDIM*NN*256 = 5.5 MB

    hipMemsetAsync(ws, 0, 1024, stream);   // header: Mcnt/done/argKey/Scnt

    k_initf<<<dim3((NN + 255) / 256, BDIM), 256, 0, stream>>>(
        logits, sig, scores, parent, compKey, selIdx, Mcnt, argKey, done, Xf8);
    k_sim_mfma<<<NT128 * BDIM, 256, 32768, stream>>>(Xf8, selIdx, Mcnt, parent);
    k_comp<<<BDIM, 1024, 0, stream>>>(parent, selIdx, Mcnt, scores, compKey, seedNode, Scnt);
    k_write<<<dim3(NDIM / 4, BDIM), 256, 0, stream>>>(sig, scores, seedNode, Scnt, out);
}

// Round 6
// 105.423 us; speedup vs baseline: 1.1215x; 1.1215x over previous
//
#include <hip/hip_runtime.h>
#include <cstdint>
#include <cstddef>

#define LDIM 6
#define BDIM 4
#define QDIM 900
#define CDIM 256
#define NDIM (LDIM*QDIM)   /* 5400 */
#define NN   5408          /* padded per-image stride */
#define T128 43            /* ceil(5400/128) */
#define NT128 (T128*(T128+1)/2) /* 946 lower-tri 128x128 tiles */

/* per-image header slots padded to one 64B cache line each to avoid
   same-line atomic serialization across blocks/images */
#define HS4 16   /* stride in ints   (64 B) */
#define HS8 8    /* stride in u64    (64 B) */

typedef float floatx4 __attribute__((ext_vector_type(4)));

__device__ __forceinline__ int sig_off(int b, int n) {
    int l = n / QDIM, q = n - l * QDIM;
    return ((l * BDIM + b) * QDIM + q) * CDIM;
}
__device__ __forceinline__ int logit_off(int b, int n) {
    int l = n / QDIM, q = n - l * QDIM;
    return (l * BDIM + b) * QDIM + q;
}

__device__ __forceinline__ int uf_load(const int* p, int i) {
    return __hip_atomic_load(&p[i], __ATOMIC_RELAXED, __HIP_MEMORY_SCOPE_AGENT);
}
__device__ int uf_find(int* p, int x) {
    int r = x;
    int pr = uf_load(p, r);
    while (pr != r) { r = pr; pr = uf_load(p, r); }
    return r;
}
__device__ void uf_union(int* p, int a, int b) {
    int ra = uf_find(p, a), rb = uf_find(p, b);
    while (ra != rb) {
        int hi = ra > rb ? ra : rb;
        int lo = ra ^ rb ^ hi;
        int old = atomicCAS(&p[hi], hi, lo);
        if (old == hi) return;
        ra = uf_find(p, old);
        rb = uf_find(p, lo);
    }
}

__device__ __forceinline__ int pk_fp8x4(float a, float b, float c, float d) {
    int p = __builtin_amdgcn_cvt_pk_fp8_f32(a, b, 0, false);   // bytes 0,1
    p = __builtin_amdgcn_cvt_pk_fp8_f32(c, d, p, true);        // bytes 2,3
    return p;
}

// K1: wide init — scores, parent, compKey=0, UNORDERED selIdx compaction (per-wave
// atomic slot claim), per-image argmax key, last-block argmax fallback.
__global__ void k_init(const float* __restrict__ logits, float* __restrict__ scores,
                       int* __restrict__ parent, unsigned long long* __restrict__ compKey,
                       int* __restrict__ selIdx, int* __restrict__ Mcnt,
                       unsigned long long* __restrict__ argKey, int* __restrict__ done) {
    int b = blockIdx.y;
    int n = blockIdx.x * 256 + threadIdx.x;
    int lane = threadIdx.x & 63;
    if (n < NN) compKey[b * NN + n] = 0ULL;
    unsigned long long key = 0ULL;
    int f = 0;
    if (n < NDIM) {
        float x = logits[logit_off(b, n)];
        float sc = 1.0f / (1.0f + expf(-x));
        scores[b * NN + n] = sc;
        parent[b * NN + n] = n;
        f = (sc >= 0.5f) ? 1 : 0;
        key = ((unsigned long long)__float_as_uint(sc) << 32) | (unsigned int)(~n);
    }
    unsigned long long bal = __ballot(f != 0);
    int cnt = __popcll(bal);
    int rank = __popcll(bal & ((1ull << lane) - 1ull));
    int base = 0;
    if (lane == 0 && cnt) base = atomicAdd(&Mcnt[b * HS4], cnt);
    base = __shfl(base, 0);
    if (f) selIdx[b * NN + base + rank] = n;
    // wave argmax -> global
    for (int off = 32; off; off >>= 1) {
        unsigned long long o = __shfl_down(key, off);
        if (o > key) key = o;
    }
    if (lane == 0) atomicMax(&argKey[b * HS8], key);
    __syncthreads();
    if (threadIdx.x == 0) {
        int prev = __hip_atomic_fetch_add(&done[b * HS4], 1, __ATOMIC_ACQ_REL,
                                          __HIP_MEMORY_SCOPE_AGENT);
        if (prev == (int)gridDim.x - 1) {   // last block: fallback if nothing selected
            if (__hip_atomic_load(&Mcnt[b * HS4], __ATOMIC_RELAXED,
                                  __HIP_MEMORY_SCOPE_AGENT) == 0) {
                unsigned long long k = __hip_atomic_load(&argKey[b * HS8], __ATOMIC_RELAXED,
                                                         __HIP_MEMORY_SCOPE_AGENT);
                selIdx[b * NN + 0] = (int)(~(unsigned int)(k & 0xffffffffULL));
                __hip_atomic_store(&Mcnt[b * HS4], 1, __ATOMIC_RELAXED,
                                   __HIP_MEMORY_SCOPE_AGENT);
            }
        }
    }
}

// K2: normalize + fp32->fp8(e4m3) compaction. Row = 256 B = 16 chunks of 16 B;
// chunk c stored at slot c ^ (g & 15). One wave per row.
__global__ void k_tobf(const float* __restrict__ sig, const int* __restrict__ selIdx,
                       const int* __restrict__ Mcnt, char* __restrict__ Xf8) {
    int b = blockIdx.y;
    int g = (blockIdx.x * blockDim.x + threadIdx.x) >> 6;
    int lane = threadIdx.x & 63;
    if (g >= min(Mcnt[b * HS4], NDIM)) return;
    int node = selIdx[b * NN + g];
    const float4 v = *(const float4*)(sig + sig_off(b, node) + lane * 4);
    float s = v.x * v.x + v.y * v.y + v.z * v.z + v.w * v.w;
    for (int off = 32; off; off >>= 1) s += __shfl_down(s, off);
    s = __shfl(s, 0);
    float ninv = rsqrtf(s + 1e-12f);
    int p = pk_fp8x4(v.x * ninv, v.y * ninv, v.z * ninv, v.w * ninv);
    int slot = (lane >> 2) ^ (g & 15);
    *(int*)(Xf8 + ((size_t)(b * NN + g)) * 256 + slot * 16 + (lane & 3) * 4) = p;
}

// K3: fp8 MFMA pairwise sims, 128x128 tiles. B tile (128 rows, 32 KB) staged to LDS;
// A rows direct from global. 16 MFMA per K-step per wave.
__global__ __launch_bounds__(256) void k_sim_mfma(const char* __restrict__ Xf8,
                                                  const int* __restrict__ selIdx,
                                                  const int* __restrict__ Mcnt,
                                                  int* __restrict__ parent) {
    int bx = blockIdx.x;
    int b = bx & 3;            // image -> XCD locality
    int t = bx >> 2;
    int M = min(Mcnt[b * HS4], NDIM);   // clamp: bounded under rocprof replay
    int ti = (int)((sqrtf(8.0f * (float)t + 1.0f) - 1.0f) * 0.5f);
    while ((ti + 1) * (ti + 2) / 2 <= t) ti++;
    while (ti * (ti + 1) / 2 > t) ti--;
    int tj = t - ti * (ti + 1) / 2;
    if (M <= 0 || ti * 128 >= M) return;

    extern __shared__ char Bs[];   // 128 rows x 256 B (swizzled layout preserved)

    int tid = threadIdx.x;
    int lane = tid & 63, wave = tid >> 6;
    int rsel = lane & 15, quad = lane >> 4;

    // stage B rows [tj*128, +128): 32 x 1KB contiguous copies (4 rows each), 8 per wave
    const char* xb = Xf8 + ((size_t)b * NN) * 256;
#pragma unroll
    for (int k = 0; k < 8; k++) {
        int i = wave * 8 + k;
        int row = min(tj * 128 + 4 * i, NN - 4);
        const char* src = xb + (size_t)row * 256 + lane * 16;
        __builtin_amdgcn_global_load_lds(
            (const __attribute__((address_space(1))) unsigned int*)src,
            (__attribute__((address_space(3))) unsigned int*)(Bs + i * 1024),
            16, 0, 0);
    }

    // A rows: wave's 32-row slab (2 x 16)
    int rA = ti * 128 + wave * 32;
    int gA0 = min(rA + rsel, M - 1);
    int gA1 = min(rA + 16 + rsel, M - 1);
    const char* pA0 = Xf8 + ((size_t)(b * NN + gA0)) * 256;
    const char* pA1 = Xf8 + ((size_t)(b * NN + gA1)) * 256;
    int swA0 = gA0 & 15, swA1 = gA1 & 15;

    __syncthreads();   // drains global_load_lds

    floatx4 acc[2][8];
#pragma unroll
    for (int s = 0; s < 2; s++)
#pragma unroll
        for (int nj = 0; nj < 8; nj++) acc[s][nj] = (floatx4){0.f, 0.f, 0.f, 0.f};

#pragma unroll
    for (int ks = 0; ks < 8; ks++) {
        int ch = ks * 2 + (quad >> 1);       // logical 16B chunk of the 32B K-slab half
        int ih = (quad & 1) * 8;             // 8B half within chunk
        long a0 = *(const long*)(pA0 + ((ch ^ swA0) << 4) + ih);
        long a1 = *(const long*)(pA1 + ((ch ^ swA1) << 4) + ih);
#pragma unroll
        for (int nj = 0; nj < 8; nj++) {
            int lr = nj * 16 + rsel;
            long bb = *(const long*)(Bs + lr * 256 + (((ch ^ (lr & 15)) << 4) + ih));
            acc[0][nj] = __builtin_amdgcn_mfma_f32_16x16x32_fp8_fp8(a0, bb, acc[0][nj], 0, 0, 0);
            acc[1][nj] = __builtin_amdgcn_mfma_f32_16x16x32_fp8_fp8(a1, bb, acc[1][nj], 0, 0, 0);
        }
    }

#pragma unroll
    for (int s = 0; s < 2; s++) {
        int rowA = rA + s * 16 + quad * 4;
#pragma unroll
        for (int nj = 0; nj < 8; nj++) {
            int gj = tj * 128 + nj * 16 + rsel;
#pragma unroll
            for (int r = 0; r < 4; r++) {
                int gi = rowA + r;
                if (gi < M && gj < M && gi > gj && acc[s][nj][r] >= 0.8f) {
                    uf_union(parent + b * NN, selIdx[b * NN + gi], selIdx[b * NN + gj]);
                }
            }
        }
    }
}

// K4: component stats + ranking. One 1024-thr block per image.
// 16 parallel wave ranges, register-cached keys, 2 syncthreads total.
__global__ __launch_bounds__(1024) void k_comp(int* __restrict__ parent,
                                               const int* __restrict__ selIdx,
                                               const int* __restrict__ Mcnt,
                                               const float* __restrict__ scores,
                                               unsigned long long* __restrict__ compKey,
                                               int* __restrict__ seedNode,
                                               int* __restrict__ Scnt) {
    int b = blockIdx.x, t = threadIdx.x;
    int lane = t & 63, w = t >> 6;      // 16 waves
    __shared__ int wcnt[16];
    __shared__ int woff[16];

    // phase 1: per selected node, find root, max packed (score, ~idx) key
    int M = min(Mcnt[b * HS4], NDIM);   // clamp: bounded under rocprof replay
    for (int base = 0; base < M; base += 1024) {
        int g = base + t;
        if (g < M) {
            int node = selIdx[b * NN + g];
            int root = uf_find(parent + b * NN, node);
            unsigned long long key =
                ((unsigned long long)__float_as_uint(scores[b * NN + node]) << 32) |
                (unsigned int)(~node);
            atomicMax(&compKey[b * NN + root], key);
        }
    }
    __syncthreads();

    // phase 2 pass A: each wave counts seeded roots in its 384-entry range,
    // caching keys in registers (agent-scope loads to bypass stale L1).
#define CROUNDS 6   /* 16 waves * 6 rounds * 64 lanes = 6144 >= NDIM */
    unsigned long long kc[CROUNDS];
    int cnt = 0;
#pragma unroll
    for (int r = 0; r < CROUNDS; r++) {
        int n = (w * CROUNDS + r) * 64 + lane;
        unsigned long long key = 0ULL;
        if (n < NDIM)
            key = __hip_atomic_load(&compKey[b * NN + n], __ATOMIC_RELAXED,
                                    __HIP_MEMORY_SCOPE_AGENT);
        kc[r] = key;
        cnt += __popcll(__ballot(key != 0ULL));
    }
    if (lane == 0) wcnt[w] = cnt;
    __syncthreads();
    if (t == 0) {
        int s = 0;
        for (int i = 0; i < 16; i++) { int v = wcnt[i]; woff[i] = s; s += v; }
        Scnt[b * HS4] = s;
    }
    __syncthreads();

    // phase 2 pass B: scatter seeds at exclusive-scanned offsets, order preserved.
    int off = woff[w];
#pragma unroll
    for (int r = 0; r < CROUNDS; r++) {
        unsigned long long bal = __ballot(kc[r] != 0ULL);
        int rank = __popcll(bal & ((1ull << lane) - 1ull));
        if (kc[r] != 0ULL)
            seedNode[b * NN + off + rank] =
                (int)(~(unsigned int)(kc[r] & 0xffffffffULL));
        off += __popcll(bal);
    }
#undef CROUNDS
}

// K5: write seed signatures / mask / scores; zero-fill empty slots. 4 rows per block.
__global__ void k_write(const float* __restrict__ sig, const float* __restrict__ scores,
                        const int* __restrict__ seedNode, const int* __restrict__ Scnt,
                        float* __restrict__ out) {
    int b = blockIdx.y;
    int slot = blockIdx.x * 4 + (threadIdx.x >> 6);
    int lane = threadIdx.x & 63;
    int S = min(Scnt[b * HS4], NDIM);   // clamp: bounded under rocprof replay
    float* orow = out + ((size_t)(b * NDIM + slot)) * CDIM + lane * 4;
    if (slot < S) {
        int s = seedNode[b * NN + slot];
        float4 v = *(const float4*)(sig + sig_off(b, s) + lane * 4);
        *(float4*)orow = v;
        if (lane == 0) {
            out[(size_t)BDIM * NDIM * CDIM + (size_t)b * NDIM + slot] = 1.0f;
            out[(size_t)BDIM * NDIM * CDIM + (size_t)BDIM * NDIM + (size_t)b * NDIM + slot] =
                scores[b * NN + s];
        }
    } else {
        float4 z = {0.f, 0.f, 0.f, 0.f};
        *(float4*)orow = z;
        if (lane == 0) {
            out[(size_t)BDIM * NDIM * CDIM + (size_t)b * NDIM + slot] = 0.0f;
            out[(size_t)BDIM * NDIM * CDIM + (size_t)BDIM * NDIM + (size_t)b * NDIM + slot] = 0.0f;
        }
    }
}

extern "C" void kernel_launch(void* const* d_in, const int* in_sizes, int n_in,
                              void* d_out, int out_size, void* d_ws, size_t ws_size,
                              hipStream_t stream) {
    (void)in_sizes; (void)n_in; (void)out_size; (void)ws_size;
    const float* sig = (const float*)d_in[0];
    const float* logits = (const float*)d_in[1];
    float* out = (float*)d_out;
    char* ws = (char*)d_ws;

    // header: 4 arrays x 4 images x 64B/line = 1024 B
    int* Mcnt = (int*)(ws + 0);                        // [b*HS4], 256 B
    int* done = (int*)(ws + 256);                      // [b*HS4], 256 B
    unsigned long long* argKey = (unsigned long long*)(ws + 512);  // [b*HS8], 256 B
    int* Scnt = (int*)(ws + 768);                      // [b*HS4], 256 B

    const size_t arr = (size_t)BDIM * NN * 4;  // 86528 B per int/float array
    unsigned long long* compKey = (unsigned long long*)(ws + 1024); // 2*arr
    float* scores = (float*)(ws + 1024 + 2 * arr);
    int* parent   = (int*)(ws + 1024 + 3 * arr);
    int* selIdx   = (int*)(ws + 1024 + 4 * arr);
    int* seedNode = (int*)(ws + 1024 + 5 * arr);
    char* Xf8     = (char*)(ws + 1024 + 6 * arr);      // BDIM*NN*256 = 5.5 MB

    hipMemsetAsync(ws, 0, 1024, stream);   // header: Mcnt/done/argKey/Scnt

    k_init<<<dim3((NN + 255) / 256, BDIM), 256, 0, stream>>>(
        logits, scores, parent, compKey, selIdx, Mcnt, argKey, done);
    k_tobf<<<dim3((NDIM + 3) / 4, BDIM), 256, 0, stream>>>(sig, selIdx, Mcnt, Xf8);
    k_sim_mfma<<<NT128 * BDIM, 256, 32768, stream>>>(Xf8, selIdx, Mcnt, parent);
    k_comp<<<BDIM, 1024, 0, stream>>>(parent, selIdx, Mcnt, scores, compKey, seedNode, Scnt);
    k_write<<<dim3(NDIM / 4, BDIM), 256, 0, stream>>>(sig, scores, seedNode, Scnt, out);
}